// Round 13
// baseline (145.635 us; speedup 1.0000x reference)
//
#include <hip/hip_runtime.h>

#define NB 8
#define NT 400
#define NN 200
#define ND 80

static constexpr float BIG_NEG = -1e30f;
static constexpr float LN2 = 0.6931471805599453f;
static constexpr float LOG2E = 1.4426950408889634f;
static constexpr float L2EPS = -99.65784284662087f;        // log(1e-30)*LOG2E
static constexpr float HALF_LOG2E = 0.7213475204444817f;   // 0.5*LOG2E
static constexpr float D_HALF_L2PI = 106.05984517680935f;  // D*0.5*log2(2pi)

static __device__ __forceinline__ float hw_exp2(float x) { return __builtin_amdgcn_exp2f(x); }
static __device__ __forceinline__ float hw_log2(float x) { return __builtin_amdgcn_logf(x); }

// fast log2(2^x + 2^y): 1 trans + cubic for log2(1+u), u in [0,1].
// Exact at u=0,1; max err ~+0.011 log2-units. Validated R7/R11/R12 (absmax 0.0).
static __device__ __forceinline__ float pl2add(float x, float y) {
    float mx = fmaxf(x, y);
    float d = fminf(x, y) - mx;            // <= 0
    float u = hw_exp2(d);                  // 2^d in [0,1]
    float p = fmaf(0.1177f, u, -0.5604f);
    p = fmaf(p, u, 1.4427f);
    return fmaf(u, p, mx);                 // mx + log2(1+u) approx
}

// log2(1 + 2^-|w|), in [0,1] (exact; parallel paths only)
static __device__ __forceinline__ float softplus2(float w) {
    return hw_log2(1.0f + hw_exp2(-fabsf(w)));
}

// whole-wave shift right by 1 lane via DPP; lane 0 receives `fill`
static __device__ __forceinline__ float wave_shr1(float x, float fill) {
    int r = __builtin_amdgcn_update_dpp(__float_as_int(fill), __float_as_int(x),
                                        0x138 /*wave_shr:1*/, 0xF, 0xF, false);
    return __int_as_float(r);
}

// ---------------------------------------------------------------------------
// Kernel 1 (log2 domain) -- byte-identical to R12 (the 76.8us best).
// ---------------------------------------------------------------------------
__global__ __launch_bounds__(256) void emission_kernel(
    const float* __restrict__ mels,   // (B,T,D)
    const float* __restrict__ means,  // (B,T,N,D)
    const float* __restrict__ stds,   // (B,T,N,D)
    const float* __restrict__ tv,     // (B,T,N)
    const int* __restrict__ inputs_len,
    const int* __restrict__ mel_lens,
    float* __restrict__ SE,           // (B,T,N) workspace
    float* __restrict__ ME)           // (B,T,N) workspace
{
    const int tid = threadIdx.x;
    const int R = blockIdx.x * 64 + (tid >> 2);  // row in [0, B*T*N)
    const int q = tid & 3;
    const int b = R / (NT * NN);
    const int r2 = R - b * (NT * NN);
    const int t = r2 / NN;
    const int n = r2 - t * NN;

    if (t >= mel_lens[b]) return;
    if (n >= inputs_len[b]) {
        if (q == 0) { SE[R] = BIG_NEG; ME[R] = BIG_NEG; }
        return;
    }

    const float4* mp = reinterpret_cast<const float4*>(means) + (size_t)R * (ND / 4) + q;
    const float4* sp = reinterpret_cast<const float4*>(stds)  + (size_t)R * (ND / 4) + q;
    const float4* xp = reinterpret_cast<const float4*>(mels)  + (size_t)(b * NT + t) * (ND / 4) + q;

    float acc = 0.f;    // sum of HALF_LOG2E * z^2
    float prod = 1.f;   // prod of 20 stds in [9.5e-7, 3325]: safe
#pragma unroll
    for (int k = 0; k < ND / 16; ++k) {
        const float4 m = mp[k * 4];
        const float4 s = sp[k * 4];
        const float4 x = xp[k * 4];
        float z0 = __fdividef(x.x - m.x, s.x);
        float z1 = __fdividef(x.y - m.y, s.y);
        float z2 = __fdividef(x.z - m.z, s.z);
        float z3 = __fdividef(x.w - m.w, s.w);
        acc = fmaf(z0 * HALF_LOG2E, z0, acc);
        acc = fmaf(z1 * HALF_LOG2E, z1, acc);
        acc = fmaf(z2 * HALF_LOG2E, z2, acc);
        acc = fmaf(z3 * HALF_LOG2E, z3, acc);
        prod *= s.x * s.y * s.z * s.w;
    }
    acc += hw_log2(prod);
    acc += __shfl_xor(acc, 1);
    acc += __shfl_xor(acc, 2);

    if (q == 0) {
        const float e2 = -acc - D_HALF_L2PI;
        if (t == 0) {
            SE[R] = e2;              // raw (log2-scaled) emission; only n==0 used
            ME[R] = BIG_NEG;
        } else {
            const size_t base = (size_t)b * NT * NN + (size_t)t * NN;
            float w = tv[base + n] * LOG2E;
            float stay2 = -(fmaxf(w, 0.f) + softplus2(w));     // log2 sigmoid(-v)
            SE[R] = e2 + fmaxf(stay2, L2EPS);
            if (n == 0) {
                ME[R] = BIG_NEG;
            } else {
                float u = tv[base + n - 1] * LOG2E;
                float mv2 = -(fmaxf(-u, 0.f) + softplus2(u));  // log2 sigmoid(v)
                ME[R] = e2 + fmaxf(mv2, L2EPS);
            }
        }
    }
}

// ---------------------------------------------------------------------------
// Kernel 2: R12's depth-16 pl2add scan, byte-identical. IDEMPOTENT: reads
// SE/ME/tv only, writes the same out[b] -- safe to launch multiple times.
// ---------------------------------------------------------------------------
__global__ __launch_bounds__(64) void scan_kernel(
    const float* __restrict__ SE,     // (B,T,N)
    const float* __restrict__ ME,     // (B,T,N)
    const float* __restrict__ tv,     // (B,T,N)
    const int* __restrict__ inputs_len,
    const int* __restrict__ mel_lens,
    float* __restrict__ out)          // (B,)
{
    const int b = blockIdx.x;
    const int lane = threadIdx.x;
    const int il = inputs_len[b];
    const int ml = mel_lens[b];
    const int mlm1 = ml - 1;
    const int cl = (lane < NN / 4) ? lane : (NN / 4 - 1);  // clamp: loads in-bounds

    const float* seb = SE + (size_t)b * NT * NN;
    const float* meb = ME + (size_t)b * NT * NN;
    const float* vb  = tv + (size_t)b * NT * NN;

    float la0 = (lane == 0) ? seb[0] : BIG_NEG;
    float la1 = BIG_NEG, la2 = BIG_NEG, la3 = BIG_NEG;

    auto ld4 = [cl](const float* p) { return reinterpret_cast<const float4*>(p)[cl]; };
#define LDT(TT) ((size_t)(((TT) <= mlm1) ? (TT) : mlm1) * NN)

#define SLOT16(OP, T0) \
    OP(1,(T0))     OP(2,(T0)+1)  OP(3,(T0)+2)  OP(4,(T0)+3)  \
    OP(5,(T0)+4)  OP(6,(T0)+5)  OP(7,(T0)+6)  OP(8,(T0)+7)  \
    OP(9,(T0)+8)  OP(10,(T0)+9) OP(11,(T0)+10) OP(12,(T0)+11) \
    OP(13,(T0)+12) OP(14,(T0)+13) OP(15,(T0)+14) OP(0,(T0)+15)

#define PRELOAD(S, TT) \
    float4 se##S = ld4(seb + LDT(TT)); \
    float4 me##S = ld4(meb + LDT(TT));
    SLOT16(PRELOAD, 1)
#undef PRELOAD

#define STEPBODY(SEV, MEV) { \
        float carry = wave_shr1(la3, BIG_NEG); \
        float a0 = la0 + SEV.x, c0 = carry + MEV.x; \
        float a1 = la1 + SEV.y, c1 = la0 + MEV.y; \
        float a2 = la2 + SEV.z, c2 = la1 + MEV.z; \
        float a3 = la3 + SEV.w, c3 = la2 + MEV.w; \
        la0 = pl2add(a0, c0); la1 = pl2add(a1, c1); \
        la2 = pl2add(a2, c2); la3 = pl2add(a3, c3); }

#define STEP(S, TT) { \
        float4 se_ = se##S, me_ = me##S; \
        se##S = ld4(seb + LDT((TT) + 16)); \
        me##S = ld4(meb + LDT((TT) + 16)); \
        STEPBODY(se_, me_) }

#define TSTEP(S, TT) if ((TT) < ml) { STEPBODY(se##S, me##S) }

    int t = 1;
    for (; t + 15 < ml; t += 16) {
        SLOT16(STEP, t)
    }
    SLOT16(TSTEP, t)   // tail: <= 15 remaining steps, slots hold t..t+15

#undef SLOT16
#undef STEP
#undef TSTEP
#undef STEPBODY
#undef LDT

    // final: only state il-1 contributes
    const int fin = il - 1;
    const int n0 = lane * 4;
    if (fin >= n0 && fin < n0 + 4) {
        float w = vb[(size_t)mlm1 * NN + fin] * LOG2E;
        float lmove2 = fmaxf(-(fmaxf(-w, 0.f) + softplus2(w)), L2EPS);
        float lastla = (fin == n0)     ? la0
                     : (fin == n0 + 1) ? la1
                     : (fin == n0 + 2) ? la2
                                       : la3;
        out[b] = LN2 * (lastla + lmove2);
    }
}

extern "C" void kernel_launch(void* const* d_in, const int* in_sizes, int n_in,
                              void* d_out, int out_size, void* d_ws, size_t ws_size,
                              hipStream_t stream) {
    const float* mels  = (const float*)d_in[0];
    const float* means = (const float*)d_in[1];
    const float* stds  = (const float*)d_in[2];
    const float* tv    = (const float*)d_in[3];
    const int* inputs_len = (const int*)d_in[4];
    const int* mel_lens   = (const int*)d_in[5];
    float* out = (float*)d_out;

    float* SE = (float*)d_ws;                    // B*T*N floats = 2.56 MB
    float* ME = SE + (size_t)NB * NT * NN;       // B*T*N floats = 2.56 MB

    const int rows = NB * NT * NN;               // 640000
    emission_kernel<<<dim3(rows / 64), dim3(256), 0, stream>>>(
        mels, means, stds, tv, inputs_len, mel_lens, SE, ME);
    // DIAGNOSTIC (R13): scan launched 3x (idempotent, same output).
    // total = E + 3S + overhead  =>  S = (total - 76.8) / 2.
    scan_kernel<<<dim3(NB), dim3(64), 0, stream>>>(
        SE, ME, tv, inputs_len, mel_lens, out);
    scan_kernel<<<dim3(NB), dim3(64), 0, stream>>>(
        SE, ME, tv, inputs_len, mel_lens, out);
    scan_kernel<<<dim3(NB), dim3(64), 0, stream>>>(
        SE, ME, tv, inputs_len, mel_lens, out);
}

// Round 14
// 76.787 us; speedup vs baseline: 1.8966x; 1.8966x over previous
//
#include <hip/hip_runtime.h>

#define NB 8
#define NT 400
#define NN 200
#define ND 80

static constexpr float BIG_NEG = -1e30f;
static constexpr float LN2 = 0.6931471805599453f;
static constexpr float LOG2E = 1.4426950408889634f;
static constexpr float L2EPS = -99.65784284662087f;        // log(1e-30)*LOG2E
static constexpr float HALF_LOG2E = 0.7213475204444817f;   // 0.5*LOG2E
static constexpr float D_HALF_L2PI = 106.05984517680935f;  // D*0.5*log2(2pi)

static __device__ __forceinline__ float hw_exp2(float x) { return __builtin_amdgcn_exp2f(x); }
static __device__ __forceinline__ float hw_log2(float x) { return __builtin_amdgcn_logf(x); }

// fast log2(2^x + 2^y): 1 trans + cubic for log2(1+u), u in [0,1].
// Exact at u=0,1; max err ~+0.011 log2-units. Validated R7/R11/R12 (absmax 0.0).
static __device__ __forceinline__ float pl2add(float x, float y) {
    float mx = fmaxf(x, y);
    float d = fminf(x, y) - mx;            // <= 0
    float u = hw_exp2(d);                  // 2^d in [0,1]
    float p = fmaf(0.1177f, u, -0.5604f);
    p = fmaf(p, u, 1.4427f);
    return fmaf(u, p, mx);                 // mx + log2(1+u) approx
}

// log2(1 + 2^-|w|), in [0,1] (exact; parallel paths only)
static __device__ __forceinline__ float softplus2(float w) {
    return hw_log2(1.0f + hw_exp2(-fabsf(w)));
}

// whole-wave shift right by 1 lane via DPP; lane 0 receives `fill`
static __device__ __forceinline__ float wave_shr1(float x, float fill) {
    int r = __builtin_amdgcn_update_dpp(__float_as_int(fill), __float_as_int(x),
                                        0x138 /*wave_shr:1*/, 0xF, 0xF, false);
    return __int_as_float(r);
}

// ---------------------------------------------------------------------------
// Kernel 1 (log2 domain) -- byte-identical to R12 (the 76.8us best).
// ---------------------------------------------------------------------------
__global__ __launch_bounds__(256) void emission_kernel(
    const float* __restrict__ mels,   // (B,T,D)
    const float* __restrict__ means,  // (B,T,N,D)
    const float* __restrict__ stds,   // (B,T,N,D)
    const float* __restrict__ tv,     // (B,T,N)
    const int* __restrict__ inputs_len,
    const int* __restrict__ mel_lens,
    float* __restrict__ SE,           // (B,T,N) workspace
    float* __restrict__ ME)           // (B,T,N) workspace
{
    const int tid = threadIdx.x;
    const int R = blockIdx.x * 64 + (tid >> 2);  // row in [0, B*T*N)
    const int q = tid & 3;
    const int b = R / (NT * NN);
    const int r2 = R - b * (NT * NN);
    const int t = r2 / NN;
    const int n = r2 - t * NN;

    if (t >= mel_lens[b]) return;
    if (n >= inputs_len[b]) {
        if (q == 0) { SE[R] = BIG_NEG; ME[R] = BIG_NEG; }
        return;
    }

    const float4* mp = reinterpret_cast<const float4*>(means) + (size_t)R * (ND / 4) + q;
    const float4* sp = reinterpret_cast<const float4*>(stds)  + (size_t)R * (ND / 4) + q;
    const float4* xp = reinterpret_cast<const float4*>(mels)  + (size_t)(b * NT + t) * (ND / 4) + q;

    float acc = 0.f;    // sum of HALF_LOG2E * z^2
    float prod = 1.f;   // prod of 20 stds in [9.5e-7, 3325]: safe
#pragma unroll
    for (int k = 0; k < ND / 16; ++k) {
        const float4 m = mp[k * 4];
        const float4 s = sp[k * 4];
        const float4 x = xp[k * 4];
        float z0 = __fdividef(x.x - m.x, s.x);
        float z1 = __fdividef(x.y - m.y, s.y);
        float z2 = __fdividef(x.z - m.z, s.z);
        float z3 = __fdividef(x.w - m.w, s.w);
        acc = fmaf(z0 * HALF_LOG2E, z0, acc);
        acc = fmaf(z1 * HALF_LOG2E, z1, acc);
        acc = fmaf(z2 * HALF_LOG2E, z2, acc);
        acc = fmaf(z3 * HALF_LOG2E, z3, acc);
        prod *= s.x * s.y * s.z * s.w;
    }
    acc += hw_log2(prod);
    acc += __shfl_xor(acc, 1);
    acc += __shfl_xor(acc, 2);

    if (q == 0) {
        const float e2 = -acc - D_HALF_L2PI;
        if (t == 0) {
            SE[R] = e2;              // raw (log2-scaled) emission; only n==0 used
            ME[R] = BIG_NEG;
        } else {
            const size_t base = (size_t)b * NT * NN + (size_t)t * NN;
            float w = tv[base + n] * LOG2E;
            float stay2 = -(fmaxf(w, 0.f) + softplus2(w));     // log2 sigmoid(-v)
            SE[R] = e2 + fmaxf(stay2, L2EPS);
            if (n == 0) {
                ME[R] = BIG_NEG;
            } else {
                float u = tv[base + n - 1] * LOG2E;
                float mv2 = -(fmaxf(-u, 0.f) + softplus2(u));  // log2 sigmoid(v)
                ME[R] = e2 + fmaxf(mv2, L2EPS);
            }
        }
    }
}

// ---------------------------------------------------------------------------
// Kernel 2: R12's depth-16 pl2add scan. SINGLE CHANGE: __launch_bounds__(64,1)
// -- min 1 wave/EU lifts the default-occupancy VGPR cap (~128) that forced
// the 16 float4-slot pairs (~180 VGPR live) into scratch, the suspected
// source of the measured ~206 cy/step (R13 diagnostic: scan = 34.4us).
// ---------------------------------------------------------------------------
__global__ __launch_bounds__(64, 1) void scan_kernel(
    const float* __restrict__ SE,     // (B,T,N)
    const float* __restrict__ ME,     // (B,T,N)
    const float* __restrict__ tv,     // (B,T,N)
    const int* __restrict__ inputs_len,
    const int* __restrict__ mel_lens,
    float* __restrict__ out)          // (B,)
{
    const int b = blockIdx.x;
    const int lane = threadIdx.x;
    const int il = inputs_len[b];
    const int ml = mel_lens[b];
    const int mlm1 = ml - 1;
    const int cl = (lane < NN / 4) ? lane : (NN / 4 - 1);  // clamp: loads in-bounds

    const float* seb = SE + (size_t)b * NT * NN;
    const float* meb = ME + (size_t)b * NT * NN;
    const float* vb  = tv + (size_t)b * NT * NN;

    float la0 = (lane == 0) ? seb[0] : BIG_NEG;
    float la1 = BIG_NEG, la2 = BIG_NEG, la3 = BIG_NEG;

    auto ld4 = [cl](const float* p) { return reinterpret_cast<const float4*>(p)[cl]; };
#define LDT(TT) ((size_t)(((TT) <= mlm1) ? (TT) : mlm1) * NN)

#define SLOT16(OP, T0) \
    OP(1,(T0))     OP(2,(T0)+1)  OP(3,(T0)+2)  OP(4,(T0)+3)  \
    OP(5,(T0)+4)  OP(6,(T0)+5)  OP(7,(T0)+6)  OP(8,(T0)+7)  \
    OP(9,(T0)+8)  OP(10,(T0)+9) OP(11,(T0)+10) OP(12,(T0)+11) \
    OP(13,(T0)+12) OP(14,(T0)+13) OP(15,(T0)+14) OP(0,(T0)+15)

#define PRELOAD(S, TT) \
    float4 se##S = ld4(seb + LDT(TT)); \
    float4 me##S = ld4(meb + LDT(TT));
    SLOT16(PRELOAD, 1)
#undef PRELOAD

#define STEPBODY(SEV, MEV) { \
        float carry = wave_shr1(la3, BIG_NEG); \
        float a0 = la0 + SEV.x, c0 = carry + MEV.x; \
        float a1 = la1 + SEV.y, c1 = la0 + MEV.y; \
        float a2 = la2 + SEV.z, c2 = la1 + MEV.z; \
        float a3 = la3 + SEV.w, c3 = la2 + MEV.w; \
        la0 = pl2add(a0, c0); la1 = pl2add(a1, c1); \
        la2 = pl2add(a2, c2); la3 = pl2add(a3, c3); }

#define STEP(S, TT) { \
        float4 se_ = se##S, me_ = me##S; \
        se##S = ld4(seb + LDT((TT) + 16)); \
        me##S = ld4(meb + LDT((TT) + 16)); \
        STEPBODY(se_, me_) }

#define TSTEP(S, TT) if ((TT) < ml) { STEPBODY(se##S, me##S) }

    int t = 1;
    for (; t + 15 < ml; t += 16) {
        SLOT16(STEP, t)
    }
    SLOT16(TSTEP, t)   // tail: <= 15 remaining steps, slots hold t..t+15

#undef SLOT16
#undef STEP
#undef TSTEP
#undef STEPBODY
#undef LDT

    // final: only state il-1 contributes
    const int fin = il - 1;
    const int n0 = lane * 4;
    if (fin >= n0 && fin < n0 + 4) {
        float w = vb[(size_t)mlm1 * NN + fin] * LOG2E;
        float lmove2 = fmaxf(-(fmaxf(-w, 0.f) + softplus2(w)), L2EPS);
        float lastla = (fin == n0)     ? la0
                     : (fin == n0 + 1) ? la1
                     : (fin == n0 + 2) ? la2
                                       : la3;
        out[b] = LN2 * (lastla + lmove2);
    }
}

extern "C" void kernel_launch(void* const* d_in, const int* in_sizes, int n_in,
                              void* d_out, int out_size, void* d_ws, size_t ws_size,
                              hipStream_t stream) {
    const float* mels  = (const float*)d_in[0];
    const float* means = (const float*)d_in[1];
    const float* stds  = (const float*)d_in[2];
    const float* tv    = (const float*)d_in[3];
    const int* inputs_len = (const int*)d_in[4];
    const int* mel_lens   = (const int*)d_in[5];
    float* out = (float*)d_out;

    float* SE = (float*)d_ws;                    // B*T*N floats = 2.56 MB
    float* ME = SE + (size_t)NB * NT * NN;       // B*T*N floats = 2.56 MB

    const int rows = NB * NT * NN;               // 640000
    emission_kernel<<<dim3(rows / 64), dim3(256), 0, stream>>>(
        mels, means, stds, tv, inputs_len, mel_lens, SE, ME);
    scan_kernel<<<dim3(NB), dim3(64), 0, stream>>>(
        SE, ME, tv, inputs_len, mel_lens, out);
}